// Round 6
// baseline (121.930 us; speedup 1.0000x reference)
//
#include <hip/hip_runtime.h>

// AdjacencyAttention: B=4096, N=64, D=256, fp32 in/out.
// Persistent-ish blocks: grid = B/4, 256 threads, 4 blocks/CU, each block
// runs 4 batches with software-pipelined x prefetch (regs) across batches:
//   dots(k from regs) -> P2 tanh->bf16 hi/lo swz LDS -> [prefetch k+1]
//   -> P3 s^T = t^T @ Vs^T (MFMA, 3-product split) -> P4 softmax -> store.
// HBM streams continuously instead of convoying at phase boundaries.

typedef float f32x4 __attribute__((ext_vector_type(4)));
typedef __bf16 bf16x8 __attribute__((ext_vector_type(8)));

constexpr int NB = 4;  // batches per block

__global__ __launch_bounds__(256, 4) void adjatt_kernel(
    const float* __restrict__ x,   // (B,64,256)
    const float* __restrict__ W1,  // (1,)
    const float* __restrict__ W2,  // (256,1)
    const float* __restrict__ W3,  // (256,)
    const float* __restrict__ bs,  // (1,64,64)
    const float* __restrict__ Vs,  // (64,64)
    float* __restrict__ out,       // (B,64,64)
    int B)
{
    __shared__ __align__(16) unsigned char tT[16384]; // [0,8K): hi bf16 [n][j] swz; [8K,16K): lo
    __shared__ __align__(16) float lhs[64];
    __shared__ __align__(16) float rhs[64];
    __shared__ __align__(16) float w2l[256];
    __shared__ __align__(16) float w3l[256];
    __shared__ float redm[4], reds[4];

    const int tid  = threadIdx.x;
    const int lane = tid & 63;
    const int w    = tid >> 6;
    const float W1v = W1[0];

    const int b0 = blockIdx.x * NB;
    const int nb = (B - b0 < NB) ? (B - b0) : NB;

    // ---- stage weights to LDS (1 float each) ----
    w2l[tid] = W2[tid];
    w3l[tid] = W3[tid];

    // ---- Vs fragments (rows 16w..16w+15), hi/lo split; B operand of MFMA ----
    // frag layout: lane l holds M[l&15][8*(l>>4)+e], e=0..7 (k-contiguous)
    bf16x8 Vh[2], Vl[2];
    {
        const int row = 16 * w + (lane & 15);
        #pragma unroll
        for (int sk = 0; sk < 2; ++sk) {
            const float* vp = Vs + row * 64 + 32 * sk + 8 * (lane >> 4);
            f32x4 f0 = *(const f32x4*)vp;
            f32x4 f1 = *(const f32x4*)(vp + 4);
            #pragma unroll
            for (int e = 0; e < 4; ++e) {
                __bf16 h0 = (__bf16)f0[e];
                Vh[sk][e] = h0;
                Vl[sk][e] = (__bf16)(f0[e] - (float)h0);
                __bf16 h1 = (__bf16)f1[e];
                Vh[sk][e + 4] = h1;
                Vl[sk][e + 4] = (__bf16)(f1[e] - (float)h1);
            }
        }
    }

    // ---- dot-phase thread mapping: 16 threads/row ----
    const int co = tid & 15;          // chunk 0..15; lanes 0..15 read 256B contig
    const int r0 = tid >> 4;          // row group 0..15 (rows r0, r0+16, +32, +48)
    const float* xbase = x + (size_t)b0 * 16384 + r0 * 256 + co * 4;

    // ---- prologue: prefetch batch b0's x-tile into registers (64 VGPR) ----
    f32x4 xp[16];
    #pragma unroll
    for (int it = 0; it < 4; ++it)
        #pragma unroll
        for (int kk = 0; kk < 4; ++kk)
            xp[it * 4 + kk] = *(const f32x4*)(xbase + it * 4096 + kk * 64);

    __syncthreads();  // weights staged

    for (int k = 0; k < nb; ++k) {
        const int b = b0 + k;

        // ---- dots: lhs[r]=(x[r]·W2)*W1, rhs[r]=x[r]·W3 from prefetched regs ----
        {
            f32x4 wv2[4], wv3[4];
            #pragma unroll
            for (int kk = 0; kk < 4; ++kk) {
                wv2[kk] = *(const f32x4*)&w2l[4 * (co + 16 * kk)];
                wv3[kk] = *(const f32x4*)&w3l[4 * (co + 16 * kk)];
            }
            #pragma unroll
            for (int it = 0; it < 4; ++it) {
                float d2 = 0.f, d3 = 0.f;
                #pragma unroll
                for (int kk = 0; kk < 4; ++kk) {
                    f32x4 xv = xp[it * 4 + kk];
                    d2 = fmaf(xv[0], wv2[kk][0], d2); d2 = fmaf(xv[1], wv2[kk][1], d2);
                    d2 = fmaf(xv[2], wv2[kk][2], d2); d2 = fmaf(xv[3], wv2[kk][3], d2);
                    d3 = fmaf(xv[0], wv3[kk][0], d3); d3 = fmaf(xv[1], wv3[kk][1], d3);
                    d3 = fmaf(xv[2], wv3[kk][2], d3); d3 = fmaf(xv[3], wv3[kk][3], d3);
                }
                d2 += __shfl_xor(d2, 1); d2 += __shfl_xor(d2, 2);
                d2 += __shfl_xor(d2, 4); d2 += __shfl_xor(d2, 8);
                d3 += __shfl_xor(d3, 1); d3 += __shfl_xor(d3, 2);
                d3 += __shfl_xor(d3, 4); d3 += __shfl_xor(d3, 8);
                if (co == 0) { lhs[r0 + 16 * it] = d2 * W1v; rhs[r0 + 16 * it] = d3; }
            }
        }
        __syncthreads();  // lhs/rhs ready

        // ---- P2: t[j][n] = tanh(lhs[j]*rhs[n] + bs[j][n]) -> tT[n][j] hi/lo ----
        {
            const int n  = lane;        // t column
            const int j0 = 16 * w;      // wave covers rows j0..j0+15
            const float rv = rhs[n];
            f32x4 lh[4];
            #pragma unroll
            for (int c = 0; c < 4; ++c) lh[c] = *(const f32x4*)&lhs[j0 + 4 * c];
            bf16x8 hi[2], lo[2];
            #pragma unroll
            for (int jj = 0; jj < 16; ++jj) {
                float z  = fmaf(lh[jj >> 2][jj & 3], rv, bs[(j0 + jj) * 64 + n]);
                float e2 = __expf(2.f * z);
                float th = 1.f - __fdividef(2.f, e2 + 1.f);  // tanh, saturates at +/-1
                __bf16 h = (__bf16)th;
                hi[jj >> 3][jj & 7] = h;
                lo[jj >> 3][jj & 7] = (__bf16)(th - (float)h);
            }
            #pragma unroll
            for (int c = 0; c < 2; ++c) {
                const int off = (n * 128 + (j0 + 8 * c) * 2) ^ ((n & 7) << 4);
                *(bf16x8*)(tT + off)        = hi[c];
                *(bf16x8*)(tT + 8192 + off) = lo[c];
            }
        }
        __syncthreads();  // tT ready

        // ---- prefetch next batch's x-tile (in flight under P3/P4/store) ----
        if (k + 1 < nb) {
            const float* xn = xbase + (size_t)(k + 1) * 16384;
            #pragma unroll
            for (int it = 0; it < 4; ++it)
                #pragma unroll
                for (int kk = 0; kk < 4; ++kk)
                    xp[it * 4 + kk] = *(const f32x4*)(xn + it * 4096 + kk * 64);
        }

        // ---- P3: s^T = t^T @ Vs^T (operand-swapped MFMA, 3-product split) ----
        f32x4 acc[4];
        #pragma unroll
        for (int ct = 0; ct < 4; ++ct) acc[ct] = (f32x4){0.f, 0.f, 0.f, 0.f};
        #pragma unroll
        for (int ct = 0; ct < 4; ++ct) {
            const int n = 16 * ct + (lane & 15);   // t column read by this lane
            #pragma unroll
            for (int sk = 0; sk < 2; ++sk) {
                const int off = (n * 128 + 64 * sk + 16 * (lane >> 4)) ^ ((n & 7) << 4);
                bf16x8 Th = *(const bf16x8*)(tT + off);
                bf16x8 Tl = *(const bf16x8*)(tT + 8192 + off);
                acc[ct] = __builtin_amdgcn_mfma_f32_16x16x32_bf16(Th, Vh[sk], acc[ct], 0, 0, 0);
                acc[ct] = __builtin_amdgcn_mfma_f32_16x16x32_bf16(Tl, Vh[sk], acc[ct], 0, 0, 0);
                acc[ct] = __builtin_amdgcn_mfma_f32_16x16x32_bf16(Th, Vl[sk], acc[ct], 0, 0, 0);
            }
        }

        // ---- P4: softmax over the 4096 scores of batch b ----
        float m = acc[0][0];
        #pragma unroll
        for (int ct = 0; ct < 4; ++ct)
            #pragma unroll
            for (int e = 0; e < 4; ++e) m = fmaxf(m, acc[ct][e]);
        #pragma unroll
        for (int off = 1; off < 64; off <<= 1) m = fmaxf(m, __shfl_xor(m, off));
        if (lane == 0) redm[w] = m;
        __syncthreads();
        const float M = fmaxf(fmaxf(redm[0], redm[1]), fmaxf(redm[2], redm[3]));

        float ssum = 0.f;
        #pragma unroll
        for (int ct = 0; ct < 4; ++ct)
            #pragma unroll
            for (int e = 0; e < 4; ++e) {
                acc[ct][e] = __expf(acc[ct][e] - M);
                ssum += acc[ct][e];
            }
        #pragma unroll
        for (int off = 1; off < 64; off <<= 1) ssum += __shfl_xor(ssum, off);
        if (lane == 0) reds[w] = ssum;
        __syncthreads();
        const float inv = __fdividef(1.f, reds[0] + reds[1] + reds[2] + reds[3]);

        // ---- store: lane holds s[16w+(l&15)][16ct + 4*(l>>4) .. +3] ----
        float* ob = out + (size_t)b * 4096 + (16 * w + (lane & 15)) * 64 + 4 * (lane >> 4);
        #pragma unroll
        for (int ct = 0; ct < 4; ++ct) {
            f32x4 v = {acc[ct][0] * inv, acc[ct][1] * inv, acc[ct][2] * inv, acc[ct][3] * inv};
            *(f32x4*)(ob + 16 * ct) = v;
        }
        // (P4's reduction barriers order tT/lhs/rhs reuse across iterations)
    }
}

extern "C" void kernel_launch(void* const* d_in, const int* in_sizes, int n_in,
                              void* d_out, int out_size, void* d_ws, size_t ws_size,
                              hipStream_t stream) {
    const float* x  = (const float*)d_in[0];
    const float* W1 = (const float*)d_in[1];
    const float* W2 = (const float*)d_in[2];
    const float* W3 = (const float*)d_in[3];
    const float* bs = (const float*)d_in[4];
    const float* Vs = (const float*)d_in[5];
    float* out = (float*)d_out;

    const int B = in_sizes[0] / (64 * 256);
    const int grid = (B + NB - 1) / NB;
    adjatt_kernel<<<dim3(grid), dim3(256), 0, stream>>>(x, W1, W2, W3, bs, Vs, out, B);
}

// Round 7
// 82.031 us; speedup vs baseline: 1.4864x; 1.4864x over previous
//
#include <hip/hip_runtime.h>

// AdjacencyAttention: B=4096, N=64, D=256, fp32 in/out.
// ONE WAVE = ONE BATCH. Zero LDS, zero barriers -> waves self-stagger and HBM
// streams continuously (no phase convoy). 256-thread blocks = 4 independent waves.
//   P1: dots; lane l ends holding lhs[l], rhs[l] (shuffle-reduced).
//   P2: t-fragments built IN REGISTERS (shfl-gathered lhs/rhs + L1-hot bs).
//   P3: s^T = t^T @ Vs^T via mfma_16x16x32_bf16, 3-product hi/lo split,
//       all 16 output tiles per lane (acc[4][4]).
//   P4: in-wave softmax butterfly over the 64 values/lane; float4 stores.

typedef float f32x4 __attribute__((ext_vector_type(4)));
typedef __bf16 bf16x8 __attribute__((ext_vector_type(8)));

__global__ __launch_bounds__(256, 3) void adjatt_kernel(
    const float* __restrict__ x,   // (B,64,256)
    const float* __restrict__ W1,  // (1,)
    const float* __restrict__ W2,  // (256,1)
    const float* __restrict__ W3,  // (256,)
    const float* __restrict__ bs,  // (1,64,64)
    const float* __restrict__ Vs,  // (64,64)
    float* __restrict__ out,       // (B,64,64)
    int B)
{
    const int tid = threadIdx.x;
    const int l   = tid & 63;
    const int wv  = tid >> 6;
    const int b   = blockIdx.x * 4 + wv;
    if (b >= B) return;

    const float W1v = W1[0];
    const int l15 = l & 15;
    const int eb  = 8 * (l >> 4);   // k-fragment base (0,8,16,24)

    // ---- P1: dots. lane l finishes holding lhs[l], rhs[l]. ----
    // Mapping: rs = l&3 (row slot), cg = l>>2 (column group). Row r = 4*it+rs.
    // Lane reads x[r][cg*4 + 64*cc], cc=0..3 -> per inst: 4 x 256B segments.
    float lhsv = 0.f, rhsv = 0.f;
    {
        const int rs = l & 3;
        const int cg = l >> 2;
        f32x4 w2v[4], w3v[4];                 // transient: dead after P1
        #pragma unroll
        for (int cc = 0; cc < 4; ++cc) {
            w2v[cc] = *(const f32x4*)(W2 + cg * 4 + 64 * cc);
            w3v[cc] = *(const f32x4*)(W3 + cg * 4 + 64 * cc);
        }
        const float* xb = x + (size_t)b * 16384 + rs * 256 + cg * 4;
        #pragma unroll
        for (int it = 0; it < 16; ++it) {
            const float* xr = xb + it * 1024;   // 4 rows per it
            float d2 = 0.f, d3 = 0.f;
            #pragma unroll
            for (int cc = 0; cc < 4; ++cc) {
                f32x4 xv = *(const f32x4*)(xr + 64 * cc);
                d2 = fmaf(xv[0], w2v[cc][0], d2); d2 = fmaf(xv[1], w2v[cc][1], d2);
                d2 = fmaf(xv[2], w2v[cc][2], d2); d2 = fmaf(xv[3], w2v[cc][3], d2);
                d3 = fmaf(xv[0], w3v[cc][0], d3); d3 = fmaf(xv[1], w3v[cc][1], d3);
                d3 = fmaf(xv[2], w3v[cc][2], d3); d3 = fmaf(xv[3], w3v[cc][3], d3);
            }
            // reduce across cg (lane bits 2..5); every lane gets row sum
            d2 += __shfl_xor(d2, 4);  d2 += __shfl_xor(d2, 8);
            d2 += __shfl_xor(d2, 16); d2 += __shfl_xor(d2, 32);
            d3 += __shfl_xor(d3, 4);  d3 += __shfl_xor(d3, 8);
            d3 += __shfl_xor(d3, 16); d3 += __shfl_xor(d3, 32);
            if (cg == it) { lhsv = d2 * W1v; rhsv = d3; }  // row 4*it+rs == l
        }
    }

    // ---- P2+P3: build t-frags in regs, MFMA into acc[rb][ct] ----
    float rn[4];
    #pragma unroll
    for (int ct = 0; ct < 4; ++ct) rn[ct] = __shfl(rhsv, 16 * ct + l15);

    f32x4 acc[4][4];
    #pragma unroll
    for (int rb = 0; rb < 4; ++rb)
        #pragma unroll
        for (int ct = 0; ct < 4; ++ct) acc[rb][ct] = (f32x4){0.f, 0.f, 0.f, 0.f};

    #pragma unroll
    for (int sk = 0; sk < 2; ++sk) {
        float lj[8];
        #pragma unroll
        for (int e = 0; e < 8; ++e) lj[e] = __shfl(lhsv, 32 * sk + eb + e);

        // t-fragments: lane l holds t[32sk+eb+e][16ct+l15], e=0..7, hi/lo split
        bf16x8 Th[4], Tl[4];
        #pragma unroll
        for (int ct = 0; ct < 4; ++ct) {
            const int n = 16 * ct + l15;
            const float* bsp = bs + (32 * sk + eb) * 64 + n;
            #pragma unroll
            for (int e = 0; e < 8; ++e) {
                float z  = fmaf(lj[e], rn[ct], bsp[e * 64]);
                float e2 = __expf(2.f * z);
                float th = 1.f - __fdividef(2.f, e2 + 1.f);  // tanh, saturates
                __bf16 h = (__bf16)th;
                Th[ct][e] = h;
                Tl[ct][e] = (__bf16)(th - (float)h);
            }
        }

        #pragma unroll
        for (int rb = 0; rb < 4; ++rb) {
            // Vs fragment (rows 16rb..16rb+15, k-slice sk), hi/lo split
            const float* vp = Vs + (16 * rb + l15) * 64 + 32 * sk + eb;
            f32x4 f0 = *(const f32x4*)vp;
            f32x4 f1 = *(const f32x4*)(vp + 4);
            bf16x8 Vh, Vl;
            #pragma unroll
            for (int e = 0; e < 4; ++e) {
                __bf16 h0 = (__bf16)f0[e];
                Vh[e] = h0;
                Vl[e] = (__bf16)(f0[e] - (float)h0);
                __bf16 h1 = (__bf16)f1[e];
                Vh[e + 4] = h1;
                Vl[e + 4] = (__bf16)(f1[e] - (float)h1);
            }
            #pragma unroll
            for (int ct = 0; ct < 4; ++ct) {
                acc[rb][ct] = __builtin_amdgcn_mfma_f32_16x16x32_bf16(Th[ct], Vh, acc[rb][ct], 0, 0, 0);
                acc[rb][ct] = __builtin_amdgcn_mfma_f32_16x16x32_bf16(Tl[ct], Vh, acc[rb][ct], 0, 0, 0);
                acc[rb][ct] = __builtin_amdgcn_mfma_f32_16x16x32_bf16(Th[ct], Vl, acc[rb][ct], 0, 0, 0);
            }
        }
    }

    // ---- P4: in-wave softmax over all 4096 scores of batch b ----
    float m = acc[0][0][0];
    #pragma unroll
    for (int rb = 0; rb < 4; ++rb)
        #pragma unroll
        for (int ct = 0; ct < 4; ++ct)
            #pragma unroll
            for (int e = 0; e < 4; ++e) m = fmaxf(m, acc[rb][ct][e]);
    #pragma unroll
    for (int off = 1; off < 64; off <<= 1) m = fmaxf(m, __shfl_xor(m, off));

    float ssum = 0.f;
    #pragma unroll
    for (int rb = 0; rb < 4; ++rb)
        #pragma unroll
        for (int ct = 0; ct < 4; ++ct)
            #pragma unroll
            for (int e = 0; e < 4; ++e) {
                acc[rb][ct][e] = __expf(acc[rb][ct][e] - m);
                ssum += acc[rb][ct][e];
            }
    #pragma unroll
    for (int off = 1; off < 64; off <<= 1) ssum += __shfl_xor(ssum, off);
    const float inv = __fdividef(1.f, ssum);

    // ---- store: lane holds s[16rb+l15][16ct+4*(l>>4) .. +3] ----
    float* ob = out + (size_t)b * 4096 + l15 * 64 + 4 * (l >> 4);
    #pragma unroll
    for (int rb = 0; rb < 4; ++rb)
        #pragma unroll
        for (int ct = 0; ct < 4; ++ct) {
            f32x4 v = {acc[rb][ct][0] * inv, acc[rb][ct][1] * inv,
                       acc[rb][ct][2] * inv, acc[rb][ct][3] * inv};
            *(f32x4*)(ob + rb * 1024 + ct * 16) = v;
        }
}

extern "C" void kernel_launch(void* const* d_in, const int* in_sizes, int n_in,
                              void* d_out, int out_size, void* d_ws, size_t ws_size,
                              hipStream_t stream) {
    const float* x  = (const float*)d_in[0];
    const float* W1 = (const float*)d_in[1];
    const float* W2 = (const float*)d_in[2];
    const float* W3 = (const float*)d_in[3];
    const float* bs = (const float*)d_in[4];
    const float* Vs = (const float*)d_in[5];
    float* out = (float*)d_out;

    const int B = in_sizes[0] / (64 * 256);
    const int grid = (B + 3) / 4;   // 4 independent waves (batches) per block
    adjatt_kernel<<<dim3(grid), dim3(256), 0, stream>>>(x, W1, W2, W3, bs, Vs, out, B);
}

// Round 8
// 71.155 us; speedup vs baseline: 1.7136x; 1.1528x over previous
//
#include <hip/hip_runtime.h>

// AdjacencyAttention: B=4096, N=64, D=256, fp32 in/out.
// One block (256 threads, 4 waves) per batch element. r2 structure (best: 69.7us)
// + launch stagger: first-generation blocks sleep g*~4.3us (g=0..3) so the 4
// resident blocks/CU interleave P1 (HBM streaming) with P2-P4 (compute) instead
// of convoying through phases in lockstep.
//   P1: lhs/rhs dots (16 thr/row, weights in regs, coalesced 256B segs)
//   P2: t = tanh(outer+bs), split into bf16 hi/lo, stored [n][j] XOR-swizzled
//   P3: s = Vs @ t via mfma_f32_16x16x32_bf16, 3-product hi/lo split
//   P4: block softmax over 4096 scores

typedef float f32x4 __attribute__((ext_vector_type(4)));
typedef __bf16 bf16x8 __attribute__((ext_vector_type(8)));

__global__ __launch_bounds__(256, 4) void adjatt_kernel(
    const float* __restrict__ x,   // (B,64,256)
    const float* __restrict__ W1,  // (1,)
    const float* __restrict__ W2,  // (256,1)
    const float* __restrict__ W3,  // (256,)
    const float* __restrict__ bs,  // (1,64,64)
    const float* __restrict__ Vs,  // (64,64)
    float* __restrict__ out)       // (B,64,64)
{
    __shared__ __align__(16) unsigned char tT[16384]; // [0,8K): hi bf16 [n][j] swz; [8K,16K): lo
    __shared__ __align__(16) float lhs[64];
    __shared__ __align__(16) float rhs[64];
    __shared__ float redm[4], reds[4];

    const int tid  = threadIdx.x;
    const int b    = blockIdx.x;
    const int lane = tid & 63;
    const int w    = tid >> 6;

    // ---- Desync co-resident blocks (first dispatch generation only).
    // Group delay ~4.3us per step; ((bid>>8)+bid)&3 varies across co-resident
    // blocks under both round-robin and CU-filling dispatch policies.
    if (b < 1024) {
        const int g = ((b >> 8) + b) & 3;
        for (int i = 0; i < g; ++i) {
            __builtin_amdgcn_s_sleep(127);   // 127*64 clocks
            __builtin_amdgcn_s_sleep(34);    // +34*64 clocks  (~10.3K total)
        }
    }

    const float W1v = W1[0];

    // ---- A fragments (Vs rows 16w..16w+15) direct from global, hi/lo split ----
    // A-frag layout (16x16x32): lane l holds A[l&15][8*(l>>4) + e], e=0..7 (k-contig)
    bf16x8 Ah[2], Al[2];
    {
        const int row = 16 * w + (lane & 15);
        #pragma unroll
        for (int s = 0; s < 2; ++s) {
            const float* vp = Vs + row * 64 + 32 * s + 8 * (lane >> 4);
            f32x4 f0 = *(const f32x4*)vp;
            f32x4 f1 = *(const f32x4*)(vp + 4);
            #pragma unroll
            for (int e = 0; e < 4; ++e) {
                __bf16 h0 = (__bf16)f0[e];
                Ah[s][e] = h0;
                Al[s][e] = (__bf16)(f0[e] - (float)h0);
                __bf16 h1 = (__bf16)f1[e];
                Ah[s][e + 4] = h1;
                Al[s][e + 4] = (__bf16)(f1[e] - (float)h1);
            }
        }
    }

    // ---- Phase 1: lhs[r] = (x[r,:]·W2)*W1 ; rhs[r] = x[r,:]·W3 ----
    {
        const int co = tid & 15;   // 16 threads per row
        const int r0 = tid >> 4;   // 0..15
        f32x4 w2v[4], w3v[4];
        #pragma unroll
        for (int kk = 0; kk < 4; ++kk) {
            w2v[kk] = *(const f32x4*)(W2 + 4 * (co + 16 * kk));
            w3v[kk] = *(const f32x4*)(W3 + 4 * (co + 16 * kk));
        }
        const float* xb = x + (size_t)b * 16384;
        #pragma unroll
        for (int it = 0; it < 4; ++it) {
            const int r = r0 + 16 * it;
            const float* xr = xb + r * 256;
            float d2 = 0.f, d3 = 0.f;
            #pragma unroll
            for (int kk = 0; kk < 4; ++kk) {
                f32x4 xv = *(const f32x4*)(xr + 4 * (co + 16 * kk));
                d2 = fmaf(xv[0], w2v[kk][0], d2); d2 = fmaf(xv[1], w2v[kk][1], d2);
                d2 = fmaf(xv[2], w2v[kk][2], d2); d2 = fmaf(xv[3], w2v[kk][3], d2);
                d3 = fmaf(xv[0], w3v[kk][0], d3); d3 = fmaf(xv[1], w3v[kk][1], d3);
                d3 = fmaf(xv[2], w3v[kk][2], d3); d3 = fmaf(xv[3], w3v[kk][3], d3);
            }
            d2 += __shfl_xor(d2, 1); d2 += __shfl_xor(d2, 2);
            d2 += __shfl_xor(d2, 4); d2 += __shfl_xor(d2, 8);
            d3 += __shfl_xor(d3, 1); d3 += __shfl_xor(d3, 2);
            d3 += __shfl_xor(d3, 4); d3 += __shfl_xor(d3, 8);
            if (co == 0) { lhs[r] = d2 * W1v; rhs[r] = d3; }
        }
    }
    __syncthreads();

    // ---- Phase 2: t[j][n] = tanh(lhs[j]*rhs[n] + bs[j][n]) -> tT[n][j] bf16 hi/lo ----
    {
        const int n  = lane;        // column
        const int j0 = 16 * w;      // this wave covers j0..j0+15
        const float rv = rhs[n];
        f32x4 lh[4];
        #pragma unroll
        for (int c = 0; c < 4; ++c) lh[c] = *(const f32x4*)&lhs[j0 + 4 * c];
        bf16x8 hi[2], lo[2];
        #pragma unroll
        for (int jj = 0; jj < 16; ++jj) {
            float z  = fmaf(lh[jj >> 2][jj & 3], rv, bs[(j0 + jj) * 64 + n]);
            float e2 = __expf(2.f * z);
            float th = 1.f - __fdividef(2.f, e2 + 1.f);  // tanh, saturates correctly
            __bf16 h = (__bf16)th;
            hi[jj >> 3][jj & 7] = h;
            lo[jj >> 3][jj & 7] = (__bf16)(th - (float)h);
        }
        #pragma unroll
        for (int c = 0; c < 2; ++c) {
            const int off = (n * 128 + (j0 + 8 * c) * 2) ^ ((n & 7) << 4);
            *(bf16x8*)(tT + off)        = hi[c];
            *(bf16x8*)(tT + 8192 + off) = lo[c];
        }
    }
    __syncthreads();

    // ---- Phase 3: s(rows 16w..16w+15, all 64 cols) = Vs @ t via MFMA ----
    // B-frag: lane l holds t[32s + 8*(l>>4) + e][16nt + (l&15)]  (k-contig in tT[n][j])
    f32x4 acc[4];
    #pragma unroll
    for (int nt = 0; nt < 4; ++nt) acc[nt] = (f32x4){0.f, 0.f, 0.f, 0.f};
    #pragma unroll
    for (int nt = 0; nt < 4; ++nt) {
        const int n = 16 * nt + (lane & 15);
        #pragma unroll
        for (int s = 0; s < 2; ++s) {
            const int off = (n * 128 + 64 * s + 16 * (lane >> 4)) ^ ((n & 7) << 4);
            bf16x8 Bh = *(const bf16x8*)(tT + off);
            bf16x8 Bl = *(const bf16x8*)(tT + 8192 + off);
            acc[nt] = __builtin_amdgcn_mfma_f32_16x16x32_bf16(Ah[s], Bh, acc[nt], 0, 0, 0);
            acc[nt] = __builtin_amdgcn_mfma_f32_16x16x32_bf16(Al[s], Bh, acc[nt], 0, 0, 0);
            acc[nt] = __builtin_amdgcn_mfma_f32_16x16x32_bf16(Ah[s], Bl, acc[nt], 0, 0, 0);
        }
    }

    // ---- Phase 4: softmax over all 4096 scores of this batch ----
    float m = acc[0][0];
    #pragma unroll
    for (int nt = 0; nt < 4; ++nt)
        #pragma unroll
        for (int e = 0; e < 4; ++e) m = fmaxf(m, acc[nt][e]);
    #pragma unroll
    for (int off = 1; off < 64; off <<= 1) m = fmaxf(m, __shfl_xor(m, off));
    if (lane == 0) redm[w] = m;
    __syncthreads();
    const float M = fmaxf(fmaxf(redm[0], redm[1]), fmaxf(redm[2], redm[3]));

    float ssum = 0.f;
    #pragma unroll
    for (int nt = 0; nt < 4; ++nt)
        #pragma unroll
        for (int e = 0; e < 4; ++e) {
            acc[nt][e] = __expf(acc[nt][e] - M);
            ssum += acc[nt][e];
        }
    #pragma unroll
    for (int off = 1; off < 64; off <<= 1) ssum += __shfl_xor(ssum, off);
    if (lane == 0) reds[w] = ssum;
    __syncthreads();
    const float inv = __fdividef(1.f, reds[0] + reds[1] + reds[2] + reds[3]);

    // ---- Store: D layout row = 16w + 4*(l>>4) + e, col = 16nt + (l&15) ----
    float* ob = out + (size_t)b * 4096;
    const int rbase = 16 * w + 4 * (lane >> 4);
    const int cbase = lane & 15;
    #pragma unroll
    for (int nt = 0; nt < 4; ++nt) {
        const int col = 16 * nt + cbase;
        #pragma unroll
        for (int e = 0; e < 4; ++e) {
            ob[(rbase + e) * 64 + col] = acc[nt][e] * inv;
        }
    }
}

extern "C" void kernel_launch(void* const* d_in, const int* in_sizes, int n_in,
                              void* d_out, int out_size, void* d_ws, size_t ws_size,
                              hipStream_t stream) {
    const float* x  = (const float*)d_in[0];
    const float* W1 = (const float*)d_in[1];
    const float* W2 = (const float*)d_in[2];
    const float* W3 = (const float*)d_in[3];
    const float* bs = (const float*)d_in[4];
    const float* Vs = (const float*)d_in[5];
    float* out = (float*)d_out;

    const int B = in_sizes[0] / (64 * 256);
    adjatt_kernel<<<dim3(B), dim3(256), 0, stream>>>(x, W1, W2, W3, bs, Vs, out);
}